// Round 1
// baseline (1399.119 us; speedup 1.0000x reference)
//
#include <hip/hip_runtime.h>
#include <math.h>

// ---------------------------------------------------------------------------
// RNN knowledge-tracing model, MI355X (gfx950).
// B=64, T=200, SKILLS=1024, C=256, H=1024.  ALL external I/O is fp32.
// Internal compute uses bf16 MFMA with fp32 accumulation.
// Round 6 changes vs round 5:
//   * h exchange rebuilt as SELF-VALIDATING TAGGED WORDS: each u64 packs
//     2 bf16 h values (lo 32) + the step tag (hi 32). Consumers poll the
//     data words themselves (relaxed agent u64 atomic loads) until
//     tag == t.  One-way store -> poll-hit-returns-data: removes the
//     exchange-return drain, the flag store and the flag->data second trip
//     (~4 coherence round trips/step -> ~1.5).  No fences anywhere.
//   * Tagged frames live in a 4-deep ring (1 MB), aliasing the dead kcv
//     region; cleared by init each launch (handles stale-tag reuse across
//     graph replays). Untagged hseq history still written (plain stores)
//     for the downstream EpiStu GEMM.
//   * Publish straight from registers: even threads pack (h[un],h[un+1])
//     via __shfl_xor — hbuf LDS + one __syncthreads per step deleted.
//   * MFMA chain split into 4 independent accumulators (dep chain 32->8).
//   * gx prefetch hoisted above the MFMA loop (latency hidden by compute).
// ---------------------------------------------------------------------------

typedef unsigned short u16;
typedef unsigned long long u64;
typedef __bf16 bf16x8 __attribute__((ext_vector_type(8)));
typedef float floatx4 __attribute__((ext_vector_type(4)));

__device__ __forceinline__ float bf2f(u16 h) {
  unsigned int u = ((unsigned int)h) << 16;
  float f;
  __builtin_memcpy(&f, &u, 4);
  return f;
}
__device__ __forceinline__ u16 f2bf(float f) {
  unsigned int u;
  __builtin_memcpy(&u, &f, 4);
  u += 0x7FFFu + ((u >> 16) & 1u);  // RNE
  return (u16)(u >> 16);
}
__device__ __forceinline__ float sigm(float x) { return 1.0f / (1.0f + __expf(-x)); }

// --- fp32 -> bf16 convert, float4 vectorized; exact grid (n % 1024 == 0) ---
__global__ void cvt_kernel(const float* __restrict__ in, u16* __restrict__ out) {
  const int i = blockIdx.x * 256 + threadIdx.x;
  const float4 v = ((const float4*)in)[i];
  ushort4 o;
  o.x = f2bf(v.x);
  o.y = f2bf(v.y);
  o.z = f2bf(v.z);
  o.w = f2bf(v.w);
  ((ushort4*)out)[i] = o;
}

// ---------------------------------------------------------------------------
// Generic 128x128-tile bf16 GEMM, C = A[M,K] @ B[N,K]^T, epilogue functor.
// ---------------------------------------------------------------------------
template <class Epi>
__global__ __launch_bounds__(256, 2) void gemm_bt(const u16* __restrict__ A,
                                                  const u16* __restrict__ B,
                                                  int M, int N, int K, Epi epi) {
  __shared__ u16 As[128 * 32];
  __shared__ u16 Bs[128 * 32];
  const int tid = threadIdx.x;
  const int w = tid >> 6, lane = tid & 63;
  const int wm = w & 1, wn = w >> 1;
  const int bm = blockIdx.x * 128, bn = blockIdx.y * 128;
  const int lrow = lane & 15, lk8 = (lane >> 4) * 8;
  const int srow = lane >> 2;        // staging: row within 16-row segment
  const int skc = (lane & 3) * 8;    // staging: k chunk (8 bf16 = 16B)

  floatx4 acc[4][4] = {};

  for (int k0 = 0; k0 < K; k0 += 32) {
#pragma unroll
    for (int r = 0; r < 2; ++r) {
      const int seg = w * 2 + r;  // 8 segments of 16 rows x 32 k
      const int row = seg * 16 + srow;
      __builtin_amdgcn_global_load_lds(
          (const __attribute__((address_space(1))) unsigned int*)(A + (size_t)(bm + row) * K + k0 + skc),
          (__attribute__((address_space(3))) unsigned int*)(As + seg * 512), 16, 0, 0);
      __builtin_amdgcn_global_load_lds(
          (const __attribute__((address_space(1))) unsigned int*)(B + (size_t)(bn + row) * K + k0 + skc),
          (__attribute__((address_space(3))) unsigned int*)(Bs + seg * 512), 16, 0, 0);
    }
    __syncthreads();

    bf16x8 af[4], bfr[4];
#pragma unroll
    for (int i = 0; i < 4; ++i) {
      af[i] = *(const bf16x8*)(As + (wm * 64 + i * 16 + lrow) * 32 + lk8);
      bfr[i] = *(const bf16x8*)(Bs + (wn * 64 + i * 16 + lrow) * 32 + lk8);
    }
#pragma unroll
    for (int i = 0; i < 4; ++i)
#pragma unroll
      for (int j = 0; j < 4; ++j)
        acc[i][j] = __builtin_amdgcn_mfma_f32_16x16x32_bf16(af[i], bfr[j], acc[i][j], 0, 0, 0);
    __syncthreads();
  }

  // C/D layout: col = lane&15, row = (lane>>4)*4 + reg  [verified m89/m91]
  const int rbase = bm + wm * 64 + (lane >> 4) * 4;
  const int cbase = bn + wn * 64 + lrow;
#pragma unroll
  for (int i = 0; i < 4; ++i)
#pragma unroll
    for (int j = 0; j < 4; ++j)
#pragma unroll
      for (int r = 0; r < 4; ++r)
        epi(rbase + i * 16 + r, cbase + j * 16, acc[i][j][r]);
}

// --- epilogues --------------------------------------------------------------
struct EpiKcVec {  // rows are b*200+t; scatter into [row][512] by result mask
  const float* bkc;
  const int* result;
  u16* kcv;
  __device__ void operator()(int row, int col, float v) const {
    v += bkc[col];
    const int off = (result[row] == 1) ? 0 : 256;
    const size_t base = (size_t)row * 512;
    kcv[base + off + col] = f2bf(v);
    kcv[base + (256 - off) + col] = 0;  // zero half
  }
};
struct EpiNk {
  const float* bkc;
  float* nk;
  __device__ void operator()(int row, int col, float v) const {
    nk[(size_t)row * 256 + col] = v + bkc[col];
  }
};
struct EpiGx {  // input row = b*200+t -> store t-major (t*64+b), bf16
  const float* bih;
  const float* bhh;
  u16* gx;
  __device__ void operator()(int row, int col, float v) const {
    v += bih[col] + bhh[col];
    const int b = row / 200, t = row - b * 200;
    gx[(size_t)(t * 64 + b) * 4096 + col] = f2bf(v);
  }
};
struct EpiStu {  // input row = t*64+b -> store fp32 at (b*200+t)*256+col
  const float* bst;
  float* out;
  __device__ void operator()(int row, int col, float v) const {
    v += bst[col];
    const int b = row & 63, t = row >> 6;
    out[(size_t)(b * 200 + t) * 256 + col] = v;
  }
};

// ---------------------------------------------------------------------------
// init: zero the 4-frame tagged h ring (4 x 32768 u64 = 1 MB).
// Frame slot 0 (tag 0, payload 0) IS the t=0 initial hidden state; slots
// 1..3 get tag 0 != wanted -> consumers spin until published. Clearing every
// launch makes graph replays safe (stale tags from a prior run never match).
// ---------------------------------------------------------------------------
__global__ void init_kernel(u64* __restrict__ htag) {
  htag[blockIdx.x * 256 + threadIdx.x] = 0ULL;
}

// ---------------------------------------------------------------------------
// LSTM scan. 256 blocks = 4 batch-groups x 64 col-groups; block owns 16
// batches x 16 h-cols. Wave w (0..3) = gate w; its W_hh slice (16 rows x
// 1024 K) lives in registers as 32 MFMA B-fragments for the whole kernel.
//
// h exchange, fence-free, ONE visibility hop:
//   word  = [tag = step | h[2c+1] | h[2c]]  (u64, relaxed AGENT atomics)
//   ring  = 4 frames x 64 batches x 512 colpair-words
//   publish: even threads pack own h + __shfl_xor neighbor, 1 atomic store.
//   consume: poll own group's 8192 words (32/thread) until tag == t; the
//            successful poll iteration already holds the data. Retries
//            reload only stale words.
// Ring-liveness: writer of frame t+1 has observed all of frame t, which
// implies every peer finished reading frame t-1; slot (t+1)&3 only aliases
// dead frame t-3. Tags make any stale overlap a retry, never a wrong read.
// ---------------------------------------------------------------------------
__global__ __launch_bounds__(256, 1) void lstm_scan(const u16* __restrict__ Whh,
                                                    const u16* __restrict__ gx,
                                                    u16* __restrict__ hseq,
                                                    u64* __restrict__ htag) {
  __shared__ __align__(16) u16 Ab[16 * 1032];  // +8 pad: 2-way bank alias (free)
  __shared__ float gbuf[4 * 256];
  const int tid = threadIdx.x;
  const int w = tid >> 6;         // gate index (torch order i,f,g,o)
  const int lane = tid & 63;
  const int lrow = lane & 15;
  const int lk8 = (lane >> 4) * 8;
  const int gb = blockIdx.x >> 6;
  const int gn = blockIdx.x & 63;
  const int bb = gb * 16;
  const int j0 = gn * 16;

  // B-fragments: W_hh[w*1024 + j0 + n][k], n = lane&15 -> 128 VGPRs, loaded once
  bf16x8 bfrag[32];
  {
    const u16* wp = Whh + (size_t)(w * 1024 + j0 + lrow) * 1024 + lk8;
#pragma unroll
    for (int ks = 0; ks < 32; ++ks) bfrag[ks] = *(const bf16x8*)(wp + ks * 32);
  }

  float c_state = 0.0f;
  const int um = tid >> 4, un = tid & 15;  // update-phase (batch, col) mapping
  const int pub = !(tid & 1);              // even threads publish colpair un/2

  // gx fetch: 4 values/thread (batch rows (lane>>4)*4+r, gate w, col j0+lrow)
  const u16* gxb = gx + (size_t)(bb + (lane >> 4) * 4) * 4096 + w * 1024 + j0 + lrow;
  u16 gcur[4];
  {
    const u16* gp = gxb;  // t = 0
    gcur[0] = gp[0];
    gcur[1] = gp[4096];
    gcur[2] = gp[8192];
    gcur[3] = gp[12288];
  }

  for (int t = 0; t < 200; ++t) {
    // ---- poll-stage h[t]: 32 tagged words/thread, retry only stale ones ----
    {
      const unsigned want = (unsigned)t;
      const u64* hw = htag + (size_t)(t & 3) * 32768 + (size_t)bb * 512 + tid;
      u64 tmp[32];
#pragma unroll
      for (int jj = 0; jj < 32; ++jj)
        tmp[jj] = __hip_atomic_load(hw + jj * 256, __ATOMIC_RELAXED,
                                    __HIP_MEMORY_SCOPE_AGENT);
      for (;;) {
        bool ok = true;
#pragma unroll
        for (int jj = 0; jj < 32; ++jj) ok &= ((unsigned)(tmp[jj] >> 32) == want);
        if (ok) break;
        __builtin_amdgcn_s_sleep(1);
#pragma unroll
        for (int jj = 0; jj < 32; ++jj)
          if ((unsigned)(tmp[jj] >> 32) != want)
            tmp[jj] = __hip_atomic_load(hw + jj * 256, __ATOMIC_RELAXED,
                                        __HIP_MEMORY_SCOPE_AGENT);
      }
      // unpack payloads -> LDS. word ch: row = ch>>9 (batch), colpair = ch&511
#pragma unroll
      for (int jj = 0; jj < 32; ++jj) {
        const int ch = jj * 256 + tid;
        const int row = ch >> 9;
        const int cp = ch & 511;
        *(unsigned*)(Ab + row * 1032 + cp * 2) = (unsigned)tmp[jj];
      }
    }
    __syncthreads();

    // acc init = gx (includes b_ih+b_hh); D layout col=lane&15, row=(lane>>4)*4+r
    floatx4 a0, a1 = {}, a2 = {}, a3 = {};
    a0[0] = bf2f(gcur[0]);
    a0[1] = bf2f(gcur[1]);
    a0[2] = bf2f(gcur[2]);
    a0[3] = bf2f(gcur[3]);

    // prefetch gx for t+1 now: HBM latency hides under the MFMA section
    if (t < 199) {
      const u16* gp = gxb + (size_t)(t + 1) * 262144;
      gcur[0] = gp[0];
      gcur[1] = gp[4096];
      gcur[2] = gp[8192];
      gcur[3] = gp[12288];
    }

    // 4 independent accumulator chains (dep chain 32 -> 8)
#pragma unroll
    for (int ks = 0; ks < 32; ks += 4) {
      const u16* ap = Ab + lrow * 1032 + ks * 32 + lk8;
      a0 = __builtin_amdgcn_mfma_f32_16x16x32_bf16(*(const bf16x8*)(ap), bfrag[ks], a0, 0, 0, 0);
      a1 = __builtin_amdgcn_mfma_f32_16x16x32_bf16(*(const bf16x8*)(ap + 32), bfrag[ks + 1], a1, 0, 0, 0);
      a2 = __builtin_amdgcn_mfma_f32_16x16x32_bf16(*(const bf16x8*)(ap + 64), bfrag[ks + 2], a2, 0, 0, 0);
      a3 = __builtin_amdgcn_mfma_f32_16x16x32_bf16(*(const bf16x8*)(ap + 96), bfrag[ks + 3], a3, 0, 0, 0);
    }
    const floatx4 acc = (a0 + a1) + (a2 + a3);
    {
      const int mrow = (lane >> 4) * 4;
#pragma unroll
      for (int r = 0; r < 4; ++r) gbuf[w * 256 + (mrow + r) * 16 + lrow] = acc[r];
    }
    __syncthreads();

    const float gi = gbuf[tid];
    const float gf = gbuf[256 + tid];
    const float gg = gbuf[512 + tid];
    const float go = gbuf[768 + tid];
    c_state = sigm(gf) * c_state + sigm(gi) * tanhf(gg);
    const float h = sigm(go) * tanhf(c_state);

    // ---- publish h[t+1] straight from registers: no hbuf, no extra sync ----
    {
      const unsigned hb = (unsigned)f2bf(h);
      const unsigned ob = (unsigned)__shfl_xor((int)hb, 1, 64);
      if (pub) {
        const unsigned lo = hb | (ob << 16);
        const u64 word = ((u64)(unsigned)(t + 1) << 32) | (u64)lo;
        __hip_atomic_store(htag + (size_t)((t + 1) & 3) * 32768 +
                               (size_t)(bb + um) * 512 + gn * 8 + (un >> 1),
                           word, __ATOMIC_RELAXED, __HIP_MEMORY_SCOPE_AGENT);
        // plain untagged history for the downstream EpiStu GEMM
        *(unsigned*)(hseq + (size_t)(t + 1) * 65536 + (size_t)(bb + um) * 1024 +
                     j0 + un) = lo;
      }
    }
    // No sync here: Ab/gbuf overwrites next iteration happen only after the
    // post-unpack __syncthreads, which every thread reaches after its reads.
  }
}

// ---------------------------------------------------------------------------
// res[b*200+t] = sum_c (stu-nk)*nk*W_out[c] + b_out ; one wave per row.
// ---------------------------------------------------------------------------
__global__ void res_kernel(const float* __restrict__ stu, const float* __restrict__ nk,
                           const float* __restrict__ Wout, const float* __restrict__ bout,
                           float* __restrict__ res) {
  const int row = blockIdx.x * 4 + (threadIdx.x >> 6);
  const int lane = threadIdx.x & 63;
  const float* sp = stu + (size_t)row * 256;
  const float* np = nk + (size_t)row * 256;
  float s = 0.0f;
#pragma unroll
  for (int j = 0; j < 4; ++j) {
    const int c = j * 64 + lane;
    const float nv = np[c];
    s += (sp[c] - nv) * nv * Wout[c];
  }
#pragma unroll
  for (int o = 32; o > 0; o >>= 1) s += __shfl_down(s, o, 64);
  if (lane == 0) res[row] = s + bout[0];
}

// ---------------------------------------------------------------------------
extern "C" void kernel_launch(void* const* d_in, const int* in_sizes, int n_in,
                              void* d_out, int out_size, void* d_ws, size_t ws_size,
                              hipStream_t stream) {
  const float* q_hot = (const float*)d_in[0];
  const int* result = (const int*)d_in[1];
  const float* next_q = (const float*)d_in[2];
  // d_in[3] = concept_num (unused, compile-time constant 256)
  const float* W_kc = (const float*)d_in[4];
  const float* b_kc = (const float*)d_in[5];
  const float* W_ih = (const float*)d_in[6];
  const float* W_hh = (const float*)d_in[7];
  const float* b_ih = (const float*)d_in[8];
  const float* b_hh = (const float*)d_in[9];
  const float* W_state = (const float*)d_in[10];
  const float* b_state = (const float*)d_in[11];
  const float* W_out = (const float*)d_in[12];
  const float* b_out = (const float*)d_in[13];

  float* out_res = (float*)d_out;       // 12800 fp32
  float* out_stu = out_res + 12800;     // 12800*256 fp32

  char* ws = (char*)d_ws;
  u16* kcv = (u16*)(ws);                        // 12800*512 bf16  = 13,107,200 B
  u64* htag = (u64*)(ws);                       // tagged h ring, 1,048,576 B --
                                                // ALIASES kcv: kcv dies after the
                                                // gx GEMM; init clears ring after.
  float* nk = (float*)(ws + 13107200);          // 12800*256 fp32  = 13,107,200 B
  u16* hseq = (u16*)(ws + 26214400);            // 201*65536 bf16  = 26,345,472 B
  u16* Whh_bf = (u16*)(ws + 52559872);          // 4096*1024 bf16  =  8,388,608 B
  u16* Wih_bf = (u16*)(ws + 60948480);          // 4096*512 bf16   =  4,194,304 B
  u16* Wkc_bf = (u16*)(ws + 65142784);          // 256*1024 bf16   =    524,288 B
  u16* Wst_bf = (u16*)(ws + 65667072);          // 256*1024 bf16   =    524,288 B
  u16* gx = (u16*)(ws + 66192384);              // 12800*4096 bf16 = 104,857,600 B
  // q_bf/nq_bf alias the gx region (dead before gx is written)
  u16* q_bf = gx;                               // 12800*1024 bf16 = 26,214,400 B
  u16* nq_bf = gx + 13107200;                   // 12800*1024 bf16
  // total ws footprint: 171,049,984 B (unchanged vs round 5)

  // fp32 -> bf16 conversions
  cvt_kernel<<<dim3(12800), 256, 0, stream>>>(q_hot, q_bf);
  cvt_kernel<<<dim3(12800), 256, 0, stream>>>(next_q, nq_bf);
  cvt_kernel<<<dim3(256), 256, 0, stream>>>(W_kc, Wkc_bf);
  cvt_kernel<<<dim3(2048), 256, 0, stream>>>(W_ih, Wih_bf);
  cvt_kernel<<<dim3(4096), 256, 0, stream>>>(W_hh, Whh_bf);
  cvt_kernel<<<dim3(256), 256, 0, stream>>>(W_state, Wst_bf);

  gemm_bt<EpiKcVec><<<dim3(100, 2), 256, 0, stream>>>(q_bf, Wkc_bf, 12800, 256, 1024,
                                                      EpiKcVec{b_kc, result, kcv});
  gemm_bt<EpiNk><<<dim3(100, 2), 256, 0, stream>>>(nq_bf, Wkc_bf, 12800, 256, 1024,
                                                   EpiNk{b_kc, nk});
  gemm_bt<EpiGx><<<dim3(100, 32), 256, 0, stream>>>(kcv, Wih_bf, 12800, 4096, 512,
                                                    EpiGx{b_ih, b_hh, gx});
  // clear the tagged ring AFTER the gx GEMM has consumed kcv (alias!)
  init_kernel<<<dim3(512), 256, 0, stream>>>(htag);
  lstm_scan<<<dim3(256), 256, 0, stream>>>(Whh_bf, gx, hseq, htag);
  gemm_bt<EpiStu><<<dim3(100, 2), 256, 0, stream>>>(hseq + 65536, Wst_bf, 12800, 256, 1024,
                                                    EpiStu{b_state, out_stu});
  res_kernel<<<dim3(3200), 256, 0, stream>>>(out_stu, nk, W_out, b_out, out_res);
}

// Round 3
// 1267.512 us; speedup vs baseline: 1.1038x; 1.1038x over previous
//
#include <hip/hip_runtime.h>
#include <math.h>

// ---------------------------------------------------------------------------
// RNN knowledge-tracing model, MI355X (gfx950).
// B=64, T=200, SKILLS=1024, C=256, H=1024.  ALL external I/O is fp32.
// Internal compute uses bf16 MFMA with fp32 accumulation.
// Round 8 changes vs round 7:
//   * FIX: grid was 64 blocks but the 512-thread geometry needs
//     (64/16 batch-groups) x (1024/32 col-groups) = 128 blocks. With 64,
//     batches 32..63 were never computed (gb only reached {0,1}) -> stale
//     hseq frames fed EpiStu (absmax 468 on stu). Protocol itself was
//     self-consistent; launch now dim3(128).
//   * Everything else unchanged from r7: r5's proven exchange protocol
//     (returning exchanges -> vmcnt(0) -> flag; poll; read quiescent frame),
//     16B sc0 sc1 read-through staging, 4-way MFMA accumulator split,
//     gx prefetch under the MFMA section.
// ---------------------------------------------------------------------------

typedef unsigned short u16;
typedef unsigned long long u64;
typedef __bf16 bf16x8 __attribute__((ext_vector_type(8)));
typedef float floatx4 __attribute__((ext_vector_type(4)));
typedef unsigned int u32x4 __attribute__((ext_vector_type(4)));

__device__ __forceinline__ float bf2f(u16 h) {
  unsigned int u = ((unsigned int)h) << 16;
  float f;
  __builtin_memcpy(&f, &u, 4);
  return f;
}
__device__ __forceinline__ u16 f2bf(float f) {
  unsigned int u;
  __builtin_memcpy(&u, &f, 4);
  u += 0x7FFFu + ((u >> 16) & 1u);  // RNE
  return (u16)(u >> 16);
}
__device__ __forceinline__ float sigm(float x) { return 1.0f / (1.0f + __expf(-x)); }

// --- fp32 -> bf16 convert, float4 vectorized; exact grid (n % 1024 == 0) ---
__global__ void cvt_kernel(const float* __restrict__ in, u16* __restrict__ out) {
  const int i = blockIdx.x * 256 + threadIdx.x;
  const float4 v = ((const float4*)in)[i];
  ushort4 o;
  o.x = f2bf(v.x);
  o.y = f2bf(v.y);
  o.z = f2bf(v.z);
  o.w = f2bf(v.w);
  ((ushort4*)out)[i] = o;
}

// ---------------------------------------------------------------------------
// Generic 128x128-tile bf16 GEMM, C = A[M,K] @ B[N,K]^T, epilogue functor.
// ---------------------------------------------------------------------------
template <class Epi>
__global__ __launch_bounds__(256, 2) void gemm_bt(const u16* __restrict__ A,
                                                  const u16* __restrict__ B,
                                                  int M, int N, int K, Epi epi) {
  __shared__ u16 As[128 * 32];
  __shared__ u16 Bs[128 * 32];
  const int tid = threadIdx.x;
  const int w = tid >> 6, lane = tid & 63;
  const int wm = w & 1, wn = w >> 1;
  const int bm = blockIdx.x * 128, bn = blockIdx.y * 128;
  const int lrow = lane & 15, lk8 = (lane >> 4) * 8;
  const int srow = lane >> 2;        // staging: row within 16-row segment
  const int skc = (lane & 3) * 8;    // staging: k chunk (8 bf16 = 16B)

  floatx4 acc[4][4] = {};

  for (int k0 = 0; k0 < K; k0 += 32) {
#pragma unroll
    for (int r = 0; r < 2; ++r) {
      const int seg = w * 2 + r;  // 8 segments of 16 rows x 32 k
      const int row = seg * 16 + srow;
      __builtin_amdgcn_global_load_lds(
          (const __attribute__((address_space(1))) unsigned int*)(A + (size_t)(bm + row) * K + k0 + skc),
          (__attribute__((address_space(3))) unsigned int*)(As + seg * 512), 16, 0, 0);
      __builtin_amdgcn_global_load_lds(
          (const __attribute__((address_space(1))) unsigned int*)(B + (size_t)(bn + row) * K + k0 + skc),
          (__attribute__((address_space(3))) unsigned int*)(Bs + seg * 512), 16, 0, 0);
    }
    __syncthreads();

    bf16x8 af[4], bfr[4];
#pragma unroll
    for (int i = 0; i < 4; ++i) {
      af[i] = *(const bf16x8*)(As + (wm * 64 + i * 16 + lrow) * 32 + lk8);
      bfr[i] = *(const bf16x8*)(Bs + (wn * 64 + i * 16 + lrow) * 32 + lk8);
    }
#pragma unroll
    for (int i = 0; i < 4; ++i)
#pragma unroll
      for (int j = 0; j < 4; ++j)
        acc[i][j] = __builtin_amdgcn_mfma_f32_16x16x32_bf16(af[i], bfr[j], acc[i][j], 0, 0, 0);
    __syncthreads();
  }

  // C/D layout: col = lane&15, row = (lane>>4)*4 + reg  [verified m89/m91]
  const int rbase = bm + wm * 64 + (lane >> 4) * 4;
  const int cbase = bn + wn * 64 + lrow;
#pragma unroll
  for (int i = 0; i < 4; ++i)
#pragma unroll
    for (int j = 0; j < 4; ++j)
#pragma unroll
      for (int r = 0; r < 4; ++r)
        epi(rbase + i * 16 + r, cbase + j * 16, acc[i][j][r]);
}

// --- epilogues --------------------------------------------------------------
struct EpiKcVec {  // rows are b*200+t; scatter into [row][512] by result mask
  const float* bkc;
  const int* result;
  u16* kcv;
  __device__ void operator()(int row, int col, float v) const {
    v += bkc[col];
    const int off = (result[row] == 1) ? 0 : 256;
    const size_t base = (size_t)row * 512;
    kcv[base + off + col] = f2bf(v);
    kcv[base + (256 - off) + col] = 0;  // zero half
  }
};
struct EpiNk {
  const float* bkc;
  float* nk;
  __device__ void operator()(int row, int col, float v) const {
    nk[(size_t)row * 256 + col] = v + bkc[col];
  }
};
struct EpiGx {  // input row = b*200+t -> store t-major (t*64+b), bf16
  const float* bih;
  const float* bhh;
  u16* gx;
  __device__ void operator()(int row, int col, float v) const {
    v += bih[col] + bhh[col];
    const int b = row / 200, t = row - b * 200;
    gx[(size_t)(t * 64 + b) * 4096 + col] = f2bf(v);
  }
};
struct EpiStu {  // input row = t*64+b -> store fp32 at (b*200+t)*256+col
  const float* bst;
  float* out;
  __device__ void operator()(int row, int col, float v) const {
    v += bst[col];
    const int b = row & 63, t = row >> 6;
    out[(size_t)(b * 200 + t) * 256 + col] = v;
  }
};

// ---------------------------------------------------------------------------
// init: zero h frame 0 (64x1024 bf16 = 128KB) + 128 barrier flags
// ---------------------------------------------------------------------------
__global__ void init_kernel(u16* hseq, unsigned* flags) {
  const int i = blockIdx.x * 256 + threadIdx.x;  // 64 blocks -> 16384 threads
  ((u64*)hseq)[i] = 0ULL;
  if (blockIdx.x == 0 && threadIdx.x < 128) flags[threadIdx.x] = 0u;
}

// ---------------------------------------------------------------------------
// LSTM scan. 128 blocks x 512 threads = 4 batch-groups x 32 col-groups;
// block owns 16 batches x 32 h-cols. Wave w (0..7): gate g = w&3, col-half
// hf = w>>2; its W_hh slice (16 rows x 1024 K) lives in registers as 32
// MFMA B-fragments for the whole kernel (128 VGPRs).
//
// Fence-free h exchange (r5 protocol, proven):
//   publish: h tile -> LDS hbuf -> wave 0: 128 relaxed AGENT u64 atomic
//            EXCHANGES (returned atomics execute at the coherence point);
//            s_waitcnt vmcnt(0) on the returns -> lane 0 relaxed flag store.
//   wait:    wave 0 polls the 32 flags of ITS batch-group, relaxed loads,
//            then __syncthreads.
//   consume: frame is QUIESCENT once all group flags >= t, so plain
//            read-through loads (global_load_dwordx4 sc0 sc1, inline asm)
//            stage it: 4 x 16B per thread — sc0+sc1 bypass L1 and the
//            per-XCD L2, so the read is serviced at the coherence point.
// ---------------------------------------------------------------------------
__global__ __launch_bounds__(512, 2) void lstm_scan(const u16* __restrict__ Whh,
                                                    const u16* __restrict__ gx,
                                                    u16* __restrict__ hseq,
                                                    unsigned* __restrict__ flags) {
  __shared__ __align__(16) u16 Ab[16 * 1032];  // +8 pad: 2-way bank alias (free)
  __shared__ float gbuf[4 * 512];
  __shared__ __align__(16) u16 hbuf[16 * 32];
  const int tid = threadIdx.x;
  const int w = tid >> 6;
  const int lane = tid & 63;
  const int lrow = lane & 15;
  const int lk8 = (lane >> 4) * 8;
  const int g = w & 3;    // gate index (torch order i,f,g,o)
  const int hf = w >> 2;  // col half (0/1) within the block's 32 cols
  const int gb = blockIdx.x >> 5;
  const int gn = blockIdx.x & 31;
  const int bb = gb * 16;
  const int j0 = gn * 32;

  // B-fragments: W_hh[g*1024 + j0 + hf*16 + lrow][k] -> 128 VGPRs, loaded once
  bf16x8 bfrag[32];
  {
    const u16* wp = Whh + (size_t)(g * 1024 + j0 + hf * 16 + lrow) * 1024 + lk8;
#pragma unroll
    for (int ks = 0; ks < 32; ++ks) bfrag[ks] = *(const bf16x8*)(wp + ks * 32);
  }

  float c_state = 0.0f;
  const int um = tid >> 5, un = tid & 31;  // update-phase (batch, col) mapping

  // gx fetch: 4 values/thread (batch rows (lane>>4)*4+r, gate g, col hf*16+lrow)
  const u16* gxb =
      gx + (size_t)(bb + (lane >> 4) * 4) * 4096 + g * 1024 + j0 + hf * 16 + lrow;
  u16 gcur[4];
  {
    const u16* gp = gxb;  // t = 0
    gcur[0] = gp[0];
    gcur[1] = gp[4096];
    gcur[2] = gp[8192];
    gcur[3] = gp[12288];
  }

  for (int t = 0; t < 200; ++t) {
    // ---- stage h[t] rows bb..bb+15 (32KB) via coherent 16B loads ----
    {
      const char* hb = (const char*)(hseq + (size_t)t * 65536 + (size_t)bb * 1024);
      const char* p0 = hb + tid * 16;
      const char* p1 = p0 + 8192;
      const char* p2 = p0 + 16384;
      const char* p3 = p0 + 24576;
      u32x4 t0, t1, t2, t3;
      asm volatile(
          "global_load_dwordx4 %0, %4, off sc0 sc1\n\t"
          "global_load_dwordx4 %1, %5, off sc0 sc1\n\t"
          "global_load_dwordx4 %2, %6, off sc0 sc1\n\t"
          "global_load_dwordx4 %3, %7, off sc0 sc1\n\t"
          "s_waitcnt vmcnt(0)"
          : "=&v"(t0), "=&v"(t1), "=&v"(t2), "=&v"(t3)
          : "v"(p0), "v"(p1), "v"(p2), "v"(p3)
          : "memory");
      // chunk ch = jj*512 + tid: row = ch>>7 (128 chunks/row), col8 = (ch&127)*8
      {
        const int ch = tid;
        *(u32x4*)(Ab + (ch >> 7) * 1032 + (ch & 127) * 8) = t0;
      }
      {
        const int ch = 512 + tid;
        *(u32x4*)(Ab + (ch >> 7) * 1032 + (ch & 127) * 8) = t1;
      }
      {
        const int ch = 1024 + tid;
        *(u32x4*)(Ab + (ch >> 7) * 1032 + (ch & 127) * 8) = t2;
      }
      {
        const int ch = 1536 + tid;
        *(u32x4*)(Ab + (ch >> 7) * 1032 + (ch & 127) * 8) = t3;
      }
    }
    __syncthreads();

    // acc init = gx (includes b_ih+b_hh); D layout col=lane&15, row=(lane>>4)*4+r
    floatx4 a0, a1 = {}, a2 = {}, a3 = {};
    a0[0] = bf2f(gcur[0]);
    a0[1] = bf2f(gcur[1]);
    a0[2] = bf2f(gcur[2]);
    a0[3] = bf2f(gcur[3]);

    // prefetch gx for t+1 now: HBM latency hides under the MFMA section
    if (t < 199) {
      const u16* gp = gxb + (size_t)(t + 1) * 262144;
      gcur[0] = gp[0];
      gcur[1] = gp[4096];
      gcur[2] = gp[8192];
      gcur[3] = gp[12288];
    }

    // 4 independent accumulator chains (dep chain 32 -> 8)
#pragma unroll
    for (int ks = 0; ks < 32; ks += 4) {
      const u16* ap = Ab + lrow * 1032 + ks * 32 + lk8;
      a0 = __builtin_amdgcn_mfma_f32_16x16x32_bf16(*(const bf16x8*)(ap), bfrag[ks], a0, 0, 0, 0);
      a1 = __builtin_amdgcn_mfma_f32_16x16x32_bf16(*(const bf16x8*)(ap + 32), bfrag[ks + 1], a1, 0, 0, 0);
      a2 = __builtin_amdgcn_mfma_f32_16x16x32_bf16(*(const bf16x8*)(ap + 64), bfrag[ks + 2], a2, 0, 0, 0);
      a3 = __builtin_amdgcn_mfma_f32_16x16x32_bf16(*(const bf16x8*)(ap + 96), bfrag[ks + 3], a3, 0, 0, 0);
    }
    const floatx4 acc = (a0 + a1) + (a2 + a3);
    {
      const int mrow = (lane >> 4) * 4;
#pragma unroll
      for (int r = 0; r < 4; ++r)
        gbuf[g * 512 + (mrow + r) * 32 + hf * 16 + lrow] = acc[r];
    }
    __syncthreads();

    const float gi = gbuf[um * 32 + un];
    const float gf = gbuf[512 + um * 32 + un];
    const float gg = gbuf[1024 + um * 32 + un];
    const float go = gbuf[1536 + um * 32 + un];
    c_state = sigm(gf) * c_state + sigm(gi) * tanhf(gg);
    const float h = sigm(go) * tanhf(c_state);
    hbuf[um * 32 + un] = f2bf(h);
    __syncthreads();

    // ---- publish: wave 0 pushes the 16x32 tile via returning exchanges ----
    if (tid < 64) {
#pragma unroll
      for (int k = 0; k < 2; ++k) {
        const int wi = k * 64 + lane;   // 128 u64 words (16 rows x 8 words)
        const int row = wi >> 3, cw = wi & 7;
        const u64 v = *(const u64*)(hbuf + row * 32 + cw * 4);
        u64 old = __hip_atomic_exchange(
            (u64*)(hseq + (size_t)(t + 1) * 65536 + (size_t)(bb + row) * 1024 +
                   j0 + cw * 4),
            v, __ATOMIC_RELAXED, __HIP_MEMORY_SCOPE_AGENT);
        asm volatile("" ::"v"(old));  // force sc0 (returning) form
      }
      asm volatile("s_waitcnt vmcnt(0)" ::: "memory");  // returns back => h at IC
      if (lane == 0)
        __hip_atomic_store(&flags[blockIdx.x], (unsigned)(t + 1), __ATOMIC_RELAXED,
                           __HIP_MEMORY_SCOPE_AGENT);

      // ---- wait: wave 0 polls own batch-group's 32 flags ----
      const unsigned tgt = (unsigned)(t + 1);
      const unsigned* gfp = &flags[gb * 32 + (lane & 31)];
      for (;;) {
        const unsigned v = __hip_atomic_load(gfp, __ATOMIC_RELAXED,
                                             __HIP_MEMORY_SCOPE_AGENT);
        if (__all(v >= tgt)) break;
        __builtin_amdgcn_s_sleep(1);
      }
    }
    __syncthreads();
  }
}

// ---------------------------------------------------------------------------
// res[b*200+t] = sum_c (stu-nk)*nk*W_out[c] + b_out ; one wave per row.
// ---------------------------------------------------------------------------
__global__ void res_kernel(const float* __restrict__ stu, const float* __restrict__ nk,
                           const float* __restrict__ Wout, const float* __restrict__ bout,
                           float* __restrict__ res) {
  const int row = blockIdx.x * 4 + (threadIdx.x >> 6);
  const int lane = threadIdx.x & 63;
  const float* sp = stu + (size_t)row * 256;
  const float* np = nk + (size_t)row * 256;
  float s = 0.0f;
#pragma unroll
  for (int j = 0; j < 4; ++j) {
    const int c = j * 64 + lane;
    const float nv = np[c];
    s += (sp[c] - nv) * nv * Wout[c];
  }
#pragma unroll
  for (int o = 32; o > 0; o >>= 1) s += __shfl_down(s, o, 64);
  if (lane == 0) res[row] = s + bout[0];
}

// ---------------------------------------------------------------------------
extern "C" void kernel_launch(void* const* d_in, const int* in_sizes, int n_in,
                              void* d_out, int out_size, void* d_ws, size_t ws_size,
                              hipStream_t stream) {
  const float* q_hot = (const float*)d_in[0];
  const int* result = (const int*)d_in[1];
  const float* next_q = (const float*)d_in[2];
  // d_in[3] = concept_num (unused, compile-time constant 256)
  const float* W_kc = (const float*)d_in[4];
  const float* b_kc = (const float*)d_in[5];
  const float* W_ih = (const float*)d_in[6];
  const float* W_hh = (const float*)d_in[7];
  const float* b_ih = (const float*)d_in[8];
  const float* b_hh = (const float*)d_in[9];
  const float* W_state = (const float*)d_in[10];
  const float* b_state = (const float*)d_in[11];
  const float* W_out = (const float*)d_in[12];
  const float* b_out = (const float*)d_in[13];

  float* out_res = (float*)d_out;       // 12800 fp32
  float* out_stu = out_res + 12800;     // 12800*256 fp32

  char* ws = (char*)d_ws;
  u16* kcv = (u16*)(ws);                        // 12800*512 bf16  = 13,107,200 B
  float* nk = (float*)(ws + 13107200);          // 12800*256 fp32  = 13,107,200 B
  u16* hseq = (u16*)(ws + 26214400);            // 201*65536 bf16  = 26,345,472 B
  u16* Whh_bf = (u16*)(ws + 52559872);          // 4096*1024 bf16  =  8,388,608 B
  u16* Wih_bf = (u16*)(ws + 60948480);          // 4096*512 bf16   =  4,194,304 B
  u16* Wkc_bf = (u16*)(ws + 65142784);          // 256*1024 bf16   =    524,288 B
  u16* Wst_bf = (u16*)(ws + 65667072);          // 256*1024 bf16   =    524,288 B
  unsigned* flags = (unsigned*)(ws + 66191360); // 128 u32 = 512 B
  u16* gx = (u16*)(ws + 66192384);              // 12800*4096 bf16 = 104,857,600 B
  // q_bf/nq_bf alias the gx region (dead before gx is written)
  u16* q_bf = gx;                               // 12800*1024 bf16 = 26,214,400 B
  u16* nq_bf = gx + 13107200;                   // 12800*1024 bf16
  // total ws footprint: 171,049,984 B

  // fp32 -> bf16 conversions
  cvt_kernel<<<dim3(12800), 256, 0, stream>>>(q_hot, q_bf);
  cvt_kernel<<<dim3(12800), 256, 0, stream>>>(next_q, nq_bf);
  cvt_kernel<<<dim3(256), 256, 0, stream>>>(W_kc, Wkc_bf);
  cvt_kernel<<<dim3(2048), 256, 0, stream>>>(W_ih, Wih_bf);
  cvt_kernel<<<dim3(4096), 256, 0, stream>>>(W_hh, Whh_bf);
  cvt_kernel<<<dim3(256), 256, 0, stream>>>(W_state, Wst_bf);

  init_kernel<<<dim3(64), 256, 0, stream>>>(hseq, flags);
  gemm_bt<EpiKcVec><<<dim3(100, 2), 256, 0, stream>>>(q_bf, Wkc_bf, 12800, 256, 1024,
                                                      EpiKcVec{b_kc, result, kcv});
  gemm_bt<EpiNk><<<dim3(100, 2), 256, 0, stream>>>(nq_bf, Wkc_bf, 12800, 256, 1024,
                                                   EpiNk{b_kc, nk});
  gemm_bt<EpiGx><<<dim3(100, 32), 256, 0, stream>>>(kcv, Wih_bf, 12800, 4096, 512,
                                                    EpiGx{b_ih, b_hh, gx});
  lstm_scan<<<dim3(128), 512, 0, stream>>>(Whh_bf, gx, hseq, flags);
  gemm_bt<EpiStu><<<dim3(100, 2), 256, 0, stream>>>(hseq + 65536, Wst_bf, 12800, 256, 1024,
                                                    EpiStu{b_state, out_stu});
  res_kernel<<<dim3(3200), 256, 0, stream>>>(out_stu, nk, W_out, b_out, out_res);
}